// Round 6
// baseline (3610.527 us; speedup 1.0000x reference)
//
#include <hip/hip_runtime.h>
#include <hip/hip_bf16.h>

// Problem constants (fixed by the reference)
#define BATCH 8
#define NPTS  4096      // N
#define CCH   128      // C
#define KNN_K 16       // K

typedef __attribute__((ext_vector_type(8))) short  bf16x8;  // 8 bf16 = 4 VGPRs
typedef __attribute__((ext_vector_type(4))) float  f32x4;   // MFMA acc

// ---------------------------------------------------------------------------
// ws layout (bytes):
//   [0)          xTb   : B*N*C bf16      = 8,388,608
//   [8388608)    Wb    : C*C  bf16       =    32,768
//   [8421376)    scale : C fp32          =       512
//   [8421888)    bias  : C fp32          =       512
//   [8422400)    pts   : B*N float4(x,y,z,s) = 524,288
//   [8946688)    knn   : B*N*K u16       = 1,048,576
// ---------------------------------------------------------------------------

static __device__ __forceinline__ short f2bf(float v) {
    __hip_bfloat16 h = __float2bfloat16(v);   // RNE
    return __builtin_bit_cast(short, h);
}

// LDS-tiled transpose: x [B,C,N] fp32 -> xTb [B,N,C] bf16.
__global__ __launch_bounds__(256) void transpose_kernel(
    const float* __restrict__ x, short* __restrict__ xTb)
{
    __shared__ short tile[64 * 66];
    const int tid = threadIdx.x;
    const int b   = blockIdx.x >> 7;         // 8 batches
    const int rem = blockIdx.x & 127;
    const int nt  = rem >> 1;                // 64 n-tiles of 64
    const int ct  = rem & 1;                 // 2 c-tiles of 64

    #pragma unroll
    for (int it = 0; it < 16; ++it) {
        const int idx = it * 256 + tid;
        const int cc  = idx >> 6;
        const int nn  = idx & 63;
        const float v = x[(size_t)(b * CCH + ct * 64 + cc) * NPTS + nt * 64 + nn];
        tile[cc * 66 + nn] = f2bf(v);
    }
    __syncthreads();
    #pragma unroll
    for (int it = 0; it < 16; ++it) {
        const int idx = it * 256 + tid;
        const int nn  = idx >> 6;
        const int cc  = idx & 63;
        xTb[(size_t)(b * NPTS + nt * 64 + nn) * CCH + ct * 64 + cc] = tile[cc * 66 + nn];
    }
}

// Small prep: W -> bf16; fold BN affine; xyz -> SoA float4 with |p|^2
__global__ __launch_bounds__(256) void small_prep_kernel(
    const float* __restrict__ xyz, const float* __restrict__ W,
    const float* __restrict__ gamma, const float* __restrict__ beta,
    const float* __restrict__ rmean, const float* __restrict__ rvar,
    short* __restrict__ Wb, float* __restrict__ scale, float* __restrict__ bias,
    float4* __restrict__ pts)
{
    const int t = blockIdx.x * 256 + threadIdx.x;   // grid covers B*N = 32768
    if (t < CCH * CCH) Wb[t] = f2bf(W[t]);
    if (t < CCH) {
        const float s = gamma[t] / sqrtf(rvar[t] + 1e-5f);
        scale[t] = s;
        bias[t]  = beta[t] - rmean[t] * s;
    }
    {
        #pragma clang fp contract(off)
        const float px = xyz[3 * t + 0];
        const float py = xyz[3 * t + 1];
        const float pz = xyz[3 * t + 2];
        const float s  = px * px + py * py + pz * pz;   // matches ref s = sum(xyz*xyz)
        pts[t] = make_float4(px, py, pz, s);
    }
}

// med3-based streaming insert into ascending top-16 (strict <: earlier j wins
// ties within an ascending-j stream). For ascending bd, the insertion shift is
// exactly bd[t]' = med3(bd[t-1], bd[t], d) -- 1 VALU op per slot.
__device__ __forceinline__ void insert16m(float bd[16], int bi[16], float d, int j) {
    bool ct[16];
    #pragma unroll
    for (int t = 0; t < 16; ++t) ct[t] = d < bd[t];
    #pragma unroll
    for (int t = 15; t >= 1; --t) {
        bi[t] = ct[t] ? (ct[t - 1] ? bi[t - 1] : j) : bi[t];
        bd[t] = __builtin_amdgcn_fmed3f(bd[t - 1], bd[t], d);
    }
    if (ct[0]) bi[0] = j;
    bd[0] = fminf(bd[0], d);
}

// Lexicographic (d, j) insert: order-independent, for cross-wave merges
__device__ __forceinline__ void insert16x(float bd[16], int bi[16], float d, int j) {
    bool lt[16];
    #pragma unroll
    for (int t = 0; t < 16; ++t) lt[t] = (d < bd[t]) || (d == bd[t] && j < bi[t]);
    #pragma unroll
    for (int t = 15; t >= 1; --t) {
        bd[t] = lt[t] ? (lt[t - 1] ? bd[t - 1] : d) : bd[t];
        bi[t] = lt[t] ? (lt[t - 1] ? bi[t - 1] : j) : bi[t];
    }
    if (lt[0]) { bd[0] = d; bi[0] = j; }
}

// KNN: block = 512 threads = 8 waves over the SAME 64 queries; wave w scans
// j in [w*512, (w+1)*512). Direct ballot-gated med3 insert (no pending
// buffer: collective hit rate ~1/iter makes buffering counterproductive).
// Tree-merge (8->4->2->1) through LDS; higher-j waves merge INTO lower-j
// waves, preserving lowest-index tie-break.
__global__ __launch_bounds__(512) void knn_kernel(
    const float4* __restrict__ pts, unsigned short* __restrict__ knn)
{
    const int lane = threadIdx.x & 63;
    const int w    = threadIdx.x >> 6;                 // 0..7
    const int b    = blockIdx.x >> 6;                  // 64 i-tiles per batch
    const int i    = ((blockIdx.x & 63) << 6) + lane;
    const float4* pb = pts + (b << 12);
    const float4 q = pb[i];

    float bd[16]; int bi[16];
    #pragma unroll
    for (int t = 0; t < 16; ++t) { bd[t] = 3.4e38f; bi[t] = 0; }

    const int jbeg = w << 9, jend = jbeg + 512;
    float4 p = pb[jbeg];
    for (int j = jbeg; j < jend; ++j) {
        const float4 pn = pb[(j + 1 < jend) ? j + 1 : jbeg];   // uniform prefetch
        float d2;
        {
            #pragma clang fp contract(off)
            const float dot = q.x * p.x + q.y * p.y + q.z * p.z;
            d2 = (q.w + p.w) - 2.0f * dot;     // s_i + s_j - 2*dot, as ref
        }
        const bool hit = d2 < bd[15];
        if (__any(hit)) insert16m(bd, bi, hit ? d2 : 3.4e38f, j);
        p = pn;
    }

    // ---- tree merge through LDS: 4 publish slots of [16][64] ----
    __shared__ float          sbd[4][16][64];
    __shared__ unsigned short sbi[4][16][64];

    if (w & 1) {
        const int s = w >> 1;
        #pragma unroll
        for (int t = 0; t < 16; ++t) { sbd[s][t][lane] = bd[t]; sbi[s][t][lane] = (unsigned short)bi[t]; }
    }
    __syncthreads();
    if (!(w & 1)) {
        const int s = w >> 1;
        #pragma unroll
        for (int t = 0; t < 16; ++t) insert16x(bd, bi, sbd[s][t][lane], (int)sbi[s][t][lane]);
    }
    __syncthreads();
    if (!(w & 1) && (w & 2)) {
        const int s = w >> 2;
        #pragma unroll
        for (int t = 0; t < 16; ++t) { sbd[s][t][lane] = bd[t]; sbi[s][t][lane] = (unsigned short)bi[t]; }
    }
    __syncthreads();
    if (!(w & 3)) {
        const int s = w >> 2;
        #pragma unroll
        for (int t = 0; t < 16; ++t) insert16x(bd, bi, sbd[s][t][lane], (int)sbi[s][t][lane]);
    }
    __syncthreads();
    if (w == 4) {
        #pragma unroll
        for (int t = 0; t < 16; ++t) { sbd[0][t][lane] = bd[t]; sbi[0][t][lane] = (unsigned short)bi[t]; }
    }
    __syncthreads();
    if (w == 0) {
        #pragma unroll
        for (int t = 0; t < 16; ++t) insert16x(bd, bi, sbd[0][t][lane], (int)sbi[0][t][lane]);
        unsigned short* o = knn + ((((size_t)b << 12) + i) << 4);
        #pragma unroll
        for (int t = 0; t < 16; ++t) o[t] = (unsigned short)bi[t];
    }
}

// Fused gather + GEMM(bf16 MFMA) + BN + ReLU + max-over-K.
// W staged in LDS (pitch 136 shorts: 272B row period -> 2-way-max bank alias).
__global__ __launch_bounds__(256) void gemm_kernel(
    const short* __restrict__ xTb, const short* __restrict__ Wb,
    const unsigned short* __restrict__ knn,
    const float* __restrict__ scale, const float* __restrict__ bias,
    float* __restrict__ out)
{
    __shared__ short sW[CCH * 136];
    const int lane = threadIdx.x & 63;
    const int wid  = threadIdx.x >> 6;
    const int b    = blockIdx.x >> 9;            // N/8 = 512 groups per batch
    const int ng   = blockIdx.x & 511;
    const int n0   = ng * 8 + wid * 2;           // this wave's two points
    const int kl   = lane & 15;                  // A: m-index = neighbor k; B: n-index = out ch
    const int c0   = (lane >> 4) * 8;            // k-dim sub-offset within 32-chunk

    #pragma unroll
    for (int it = 0; it < 8; ++it) {             // stage W: 16384 elems, 16B chunks
        const int e = (it * 256 + threadIdx.x) * 8;
        const int r = e >> 7, c = e & 127;
        *(bf16x8*)(sW + r * 136 + c) = *(const bf16x8*)(Wb + e);
    }

    int rowoff[2];
    #pragma unroll
    for (int p = 0; p < 2; ++p) {
        const int n = n0 + p;
        const int r = (int)knn[(((size_t)b * NPTS + n) << 4) + kl];
        rowoff[p] = (b * NPTS + r) * CCH;        // element offset into xTb
    }
    __syncthreads();

    const f32x4 zero = {0.f, 0.f, 0.f, 0.f};
    f32x4 acc[2][8];
    #pragma unroll
    for (int p = 0; p < 2; ++p)
        #pragma unroll
        for (int t = 0; t < 8; ++t) acc[p][t] = zero;

    #pragma unroll
    for (int kk = 0; kk < 4; ++kk) {             // K = 128 channels, 32 per MFMA
        const int cb = kk * 32 + c0;
        bf16x8 a0 = *(const bf16x8*)(xTb + rowoff[0] + cb);
        bf16x8 a1 = *(const bf16x8*)(xTb + rowoff[1] + cb);
        #pragma unroll
        for (int t = 0; t < 8; ++t) {
            const bf16x8 bf = *(const bf16x8*)(sW + (t * 16 + kl) * 136 + cb);
            acc[0][t] = __builtin_amdgcn_mfma_f32_16x16x32_bf16(a0, bf, acc[0][t], 0, 0, 0);
            acc[1][t] = __builtin_amdgcn_mfma_f32_16x16x32_bf16(a1, bf, acc[1][t], 0, 0, 0);
        }
    }

    #pragma unroll
    for (int t = 0; t < 8; ++t) {
        const int o = t * 16 + kl;
        const float s  = scale[o];
        const float bb = bias[o];
        #pragma unroll
        for (int p = 0; p < 2; ++p) {
            const f32x4 v = acc[p][t];
            float mx = 0.f;                      // relu floor: max_k relu(y) = max(0, max_k y)
            #pragma unroll
            for (int r = 0; r < 4; ++r) mx = fmaxf(mx, v[r] * s + bb);
            mx = fmaxf(mx, __shfl_xor(mx, 16));
            mx = fmaxf(mx, __shfl_xor(mx, 32));
            if (lane < 16) out[(size_t)(b * CCH + o) * NPTS + (n0 + p)] = mx;
        }
    }
}

extern "C" void kernel_launch(void* const* d_in, const int* in_sizes, int n_in,
                              void* d_out, int out_size, void* d_ws, size_t ws_size,
                              hipStream_t stream)
{
    const float* xyz   = (const float*)d_in[0];
    const float* x     = (const float*)d_in[1];
    const float* W     = (const float*)d_in[2];
    const float* gamma = (const float*)d_in[3];
    const float* beta  = (const float*)d_in[4];
    const float* rmean = (const float*)d_in[5];
    const float* rvar  = (const float*)d_in[6];
    float* out = (float*)d_out;

    char* ws = (char*)d_ws;
    short*          xTb   = (short*)(ws);
    short*          Wb    = (short*)(ws + 8388608);
    float*          scale = (float*)(ws + 8421376);
    float*          bias  = (float*)(ws + 8421888);
    float4*         pts   = (float4*)(ws + 8422400);
    unsigned short* knn   = (unsigned short*)(ws + 8946688);

    transpose_kernel<<<BATCH * 64 * 2, 256, 0, stream>>>(x, xTb);
    small_prep_kernel<<<BATCH * NPTS / 256, 256, 0, stream>>>(
        xyz, W, gamma, beta, rmean, rvar, Wb, scale, bias, pts);
    knn_kernel<<<BATCH * 64, 512, 0, stream>>>(pts, knn);
    gemm_kernel<<<BATCH * (NPTS / 8), 256, 0, stream>>>(xTb, Wb, knn, scale, bias, out);
}

// Round 7
// 329.178 us; speedup vs baseline: 10.9683x; 10.9683x over previous
//
#include <hip/hip_runtime.h>
#include <hip/hip_bf16.h>

// Problem constants (fixed by the reference)
#define BATCH 8
#define NPTS  4096      // N
#define CCH   128      // C
#define KNN_K 16       // K

typedef __attribute__((ext_vector_type(8))) short  bf16x8;  // 8 bf16 = 4 VGPRs
typedef __attribute__((ext_vector_type(4))) float  f32x4;   // MFMA acc

// ---------------------------------------------------------------------------
// ws layout (bytes):
//   [0)          xTb   : B*N*C bf16      = 8,388,608
//   [8388608)    Wb    : C*C  bf16       =    32,768
//   [8421376)    scale : C fp32          =       512
//   [8421888)    bias  : C fp32          =       512
//   [8422400)    pts   : B*N float4(x,y,z,s) = 524,288
//   [8946688)    knn   : B*N*K u16       = 1,048,576
// ---------------------------------------------------------------------------

static __device__ __forceinline__ short f2bf(float v) {
    __hip_bfloat16 h = __float2bfloat16(v);   // RNE
    return __builtin_bit_cast(short, h);
}

// LDS-tiled transpose: x [B,C,N] fp32 -> xTb [B,N,C] bf16.
__global__ __launch_bounds__(256) void transpose_kernel(
    const float* __restrict__ x, short* __restrict__ xTb)
{
    __shared__ short tile[64 * 66];
    const int tid = threadIdx.x;
    const int b   = blockIdx.x >> 7;         // 8 batches
    const int rem = blockIdx.x & 127;
    const int nt  = rem >> 1;                // 64 n-tiles of 64
    const int ct  = rem & 1;                 // 2 c-tiles of 64

    #pragma unroll
    for (int it = 0; it < 16; ++it) {
        const int idx = it * 256 + tid;
        const int cc  = idx >> 6;
        const int nn  = idx & 63;
        const float v = x[(size_t)(b * CCH + ct * 64 + cc) * NPTS + nt * 64 + nn];
        tile[cc * 66 + nn] = f2bf(v);
    }
    __syncthreads();
    #pragma unroll
    for (int it = 0; it < 16; ++it) {
        const int idx = it * 256 + tid;
        const int nn  = idx >> 6;
        const int cc  = idx & 63;
        xTb[(size_t)(b * NPTS + nt * 64 + nn) * CCH + ct * 64 + cc] = tile[cc * 66 + nn];
    }
}

// Small prep: W -> bf16; fold BN affine; xyz -> SoA float4 with |p|^2
__global__ __launch_bounds__(256) void small_prep_kernel(
    const float* __restrict__ xyz, const float* __restrict__ W,
    const float* __restrict__ gamma, const float* __restrict__ beta,
    const float* __restrict__ rmean, const float* __restrict__ rvar,
    short* __restrict__ Wb, float* __restrict__ scale, float* __restrict__ bias,
    float4* __restrict__ pts)
{
    const int t = blockIdx.x * 256 + threadIdx.x;   // grid covers B*N = 32768
    if (t < CCH * CCH) Wb[t] = f2bf(W[t]);
    if (t < CCH) {
        const float s = gamma[t] / sqrtf(rvar[t] + 1e-5f);
        scale[t] = s;
        bias[t]  = beta[t] - rmean[t] * s;
    }
    {
        #pragma clang fp contract(off)
        const float px = xyz[3 * t + 0];
        const float py = xyz[3 * t + 1];
        const float pz = xyz[3 * t + 2];
        const float s  = px * px + py * py + pz * pz;   // matches ref s = sum(xyz*xyz)
        pts[t] = make_float4(px, py, pz, s);
    }
}

// Wave-per-query KNN. The top-16 list lives ACROSS lanes (lane l of 0..15
// holds the l-th smallest distance + index) -- no per-lane arrays, no spill
// risk. Each chunk: 64 lanes compute 64 distinct candidate distances in
// parallel; survivors (d2 < tau, strict) are ballot-compacted and inserted
// serially via a wave-uniform shuffle-shift. Chunks ascending + ctz ascending
// => ascending-j stream; strict < preserves reference lowest-index tie-break.
// Stale-tau survivors self-reject inside the insert (no-op).
__global__ __launch_bounds__(256) void knn_kernel(
    const float4* __restrict__ pts, unsigned short* __restrict__ knn)
{
    const int lane = threadIdx.x & 63;
    const int wid  = threadIdx.x >> 6;
    const int qid  = blockIdx.x * 4 + wid;     // one wave per query
    const int b    = qid >> 12;
    const int i    = qid & 4095;
    const float4* pb = pts + (b << 12);

    const float4 q = pb[i];                    // wave-uniform

    float bd = 3.4e38f;                        // lane l: l-th smallest (l<16)
    int   bj = 0;
    float tau = 3.4e38f;
    const bool lgt0 = (lane > 0);

    for (int ch = 0; ch < 64; ++ch) {
        const float4 p = pb[(ch << 6) + lane];
        float d2;
        {
            #pragma clang fp contract(off)
            const float dot = q.x * p.x + q.y * p.y + q.z * p.z;
            d2 = (q.w + p.w) - 2.0f * dot;     // s_i + s_j - 2*dot, as ref
        }
        unsigned long long mask = __ballot(d2 < tau);
        while (mask) {
            const int l = __builtin_ctzll(mask);
            mask &= mask - 1;
            const float dv = __shfl(d2, l);    // wave-uniform survivor
            const int   jv = (ch << 6) + l;
            // cross-lane sorted insert (ascending lanes 0..15)
            const float pd = __shfl_up(bd, 1);
            const int   pj = __shfl_up(bj, 1);
            const bool lt  = dv < bd;
            const bool ltp = lgt0 && (dv < pd);
            bd = lt ? (ltp ? pd : dv) : bd;
            bj = lt ? (ltp ? pj : jv) : bj;
            tau = __shfl(bd, 15);
        }
    }

    if (lane < 16) {
        unsigned short* o = knn + ((((size_t)b << 12) + i) << 4);
        o[lane] = (unsigned short)bj;
    }
}

// Fused gather + GEMM(bf16 MFMA) + BN + ReLU + max-over-K.
// W staged in LDS (pitch 136 shorts: 272B row period -> 2-way-max bank alias).
__global__ __launch_bounds__(256) void gemm_kernel(
    const short* __restrict__ xTb, const short* __restrict__ Wb,
    const unsigned short* __restrict__ knn,
    const float* __restrict__ scale, const float* __restrict__ bias,
    float* __restrict__ out)
{
    __shared__ short sW[CCH * 136];
    const int lane = threadIdx.x & 63;
    const int wid  = threadIdx.x >> 6;
    const int b    = blockIdx.x >> 9;            // N/8 = 512 groups per batch
    const int ng   = blockIdx.x & 511;
    const int n0   = ng * 8 + wid * 2;           // this wave's two points
    const int kl   = lane & 15;                  // A: m-index = neighbor k; B: n-index = out ch
    const int c0   = (lane >> 4) * 8;            // k-dim sub-offset within 32-chunk

    #pragma unroll
    for (int it = 0; it < 8; ++it) {             // stage W: 16384 elems, 16B chunks
        const int e = (it * 256 + threadIdx.x) * 8;
        const int r = e >> 7, c = e & 127;
        *(bf16x8*)(sW + r * 136 + c) = *(const bf16x8*)(Wb + e);
    }

    int rowoff[2];
    #pragma unroll
    for (int p = 0; p < 2; ++p) {
        const int n = n0 + p;
        const int r = (int)knn[(((size_t)b * NPTS + n) << 4) + kl];
        rowoff[p] = (b * NPTS + r) * CCH;        // element offset into xTb
    }
    __syncthreads();

    const f32x4 zero = {0.f, 0.f, 0.f, 0.f};
    f32x4 acc[2][8];
    #pragma unroll
    for (int p = 0; p < 2; ++p)
        #pragma unroll
        for (int t = 0; t < 8; ++t) acc[p][t] = zero;

    #pragma unroll
    for (int kk = 0; kk < 4; ++kk) {             // K = 128 channels, 32 per MFMA
        const int cb = kk * 32 + c0;
        bf16x8 a0 = *(const bf16x8*)(xTb + rowoff[0] + cb);
        bf16x8 a1 = *(const bf16x8*)(xTb + rowoff[1] + cb);
        #pragma unroll
        for (int t = 0; t < 8; ++t) {
            const bf16x8 bf = *(const bf16x8*)(sW + (t * 16 + kl) * 136 + cb);
            acc[0][t] = __builtin_amdgcn_mfma_f32_16x16x32_bf16(a0, bf, acc[0][t], 0, 0, 0);
            acc[1][t] = __builtin_amdgcn_mfma_f32_16x16x32_bf16(a1, bf, acc[1][t], 0, 0, 0);
        }
    }

    #pragma unroll
    for (int t = 0; t < 8; ++t) {
        const int o = t * 16 + kl;
        const float s  = scale[o];
        const float bb = bias[o];
        #pragma unroll
        for (int p = 0; p < 2; ++p) {
            const f32x4 v = acc[p][t];
            float mx = 0.f;                      // relu floor: max_k relu(y) = max(0, max_k y)
            #pragma unroll
            for (int r = 0; r < 4; ++r) mx = fmaxf(mx, v[r] * s + bb);
            mx = fmaxf(mx, __shfl_xor(mx, 16));
            mx = fmaxf(mx, __shfl_xor(mx, 32));
            if (lane < 16) out[(size_t)(b * CCH + o) * NPTS + (n0 + p)] = mx;
        }
    }
}

extern "C" void kernel_launch(void* const* d_in, const int* in_sizes, int n_in,
                              void* d_out, int out_size, void* d_ws, size_t ws_size,
                              hipStream_t stream)
{
    const float* xyz   = (const float*)d_in[0];
    const float* x     = (const float*)d_in[1];
    const float* W     = (const float*)d_in[2];
    const float* gamma = (const float*)d_in[3];
    const float* beta  = (const float*)d_in[4];
    const float* rmean = (const float*)d_in[5];
    const float* rvar  = (const float*)d_in[6];
    float* out = (float*)d_out;

    char* ws = (char*)d_ws;
    short*          xTb   = (short*)(ws);
    short*          Wb    = (short*)(ws + 8388608);
    float*          scale = (float*)(ws + 8421376);
    float*          bias  = (float*)(ws + 8421888);
    float4*         pts   = (float4*)(ws + 8422400);
    unsigned short* knn   = (unsigned short*)(ws + 8946688);

    transpose_kernel<<<BATCH * 64 * 2, 256, 0, stream>>>(x, xTb);
    small_prep_kernel<<<BATCH * NPTS / 256, 256, 0, stream>>>(
        xyz, W, gamma, beta, rmean, rvar, Wb, scale, bias, pts);
    knn_kernel<<<BATCH * NPTS / 4, 256, 0, stream>>>(pts, knn);
    gemm_kernel<<<BATCH * (NPTS / 8), 256, 0, stream>>>(xTb, Wb, knn, scale, bias, out);
}

// Round 8
// 237.560 us; speedup vs baseline: 15.1984x; 1.3857x over previous
//
#include <hip/hip_runtime.h>
#include <hip/hip_bf16.h>

// Problem constants (fixed by the reference)
#define BATCH 8
#define NPTS  4096      // N
#define CCH   128      // C
#define KNN_K 16       // K

typedef __attribute__((ext_vector_type(8))) short  bf16x8;  // 8 bf16 = 4 VGPRs
typedef __attribute__((ext_vector_type(4))) float  f32x4;   // MFMA acc

// ---------------------------------------------------------------------------
// ws layout (bytes):
//   [0)          xTb   : B*N*C bf16      = 8,388,608
//   [8388608)    Wb    : C*C  bf16       =    32,768
//   [8421376)    scale : C fp32          =       512
//   [8421888)    bias  : C fp32          =       512
//   [8422400)    pts   : B*N float4(x,y,z,s) = 524,288
//   [8946688)    knn   : B*N*K u16       = 1,048,576
// ---------------------------------------------------------------------------

static __device__ __forceinline__ short f2bf(float v) {
    __hip_bfloat16 h = __float2bfloat16(v);   // RNE
    return __builtin_bit_cast(short, h);
}

// LDS-tiled transpose: x [B,C,N] fp32 -> xTb [B,N,C] bf16.
__global__ __launch_bounds__(256) void transpose_kernel(
    const float* __restrict__ x, short* __restrict__ xTb)
{
    __shared__ short tile[64 * 66];
    const int tid = threadIdx.x;
    const int b   = blockIdx.x >> 7;         // 8 batches
    const int rem = blockIdx.x & 127;
    const int nt  = rem >> 1;                // 64 n-tiles of 64
    const int ct  = rem & 1;                 // 2 c-tiles of 64

    #pragma unroll
    for (int it = 0; it < 16; ++it) {
        const int idx = it * 256 + tid;
        const int cc  = idx >> 6;
        const int nn  = idx & 63;
        const float v = x[(size_t)(b * CCH + ct * 64 + cc) * NPTS + nt * 64 + nn];
        tile[cc * 66 + nn] = f2bf(v);
    }
    __syncthreads();
    #pragma unroll
    for (int it = 0; it < 16; ++it) {
        const int idx = it * 256 + tid;
        const int nn  = idx >> 6;
        const int cc  = idx & 63;
        xTb[(size_t)(b * NPTS + nt * 64 + nn) * CCH + ct * 64 + cc] = tile[cc * 66 + nn];
    }
}

// Small prep: W -> bf16; fold BN affine; xyz -> SoA float4 with |p|^2
__global__ __launch_bounds__(256) void small_prep_kernel(
    const float* __restrict__ xyz, const float* __restrict__ W,
    const float* __restrict__ gamma, const float* __restrict__ beta,
    const float* __restrict__ rmean, const float* __restrict__ rvar,
    short* __restrict__ Wb, float* __restrict__ scale, float* __restrict__ bias,
    float4* __restrict__ pts)
{
    const int t = blockIdx.x * 256 + threadIdx.x;   // grid covers B*N = 32768
    if (t < CCH * CCH) Wb[t] = f2bf(W[t]);
    if (t < CCH) {
        const float s = gamma[t] / sqrtf(rvar[t] + 1e-5f);
        scale[t] = s;
        bias[t]  = beta[t] - rmean[t] * s;
    }
    {
        #pragma clang fp contract(off)
        const float px = xyz[3 * t + 0];
        const float py = xyz[3 * t + 1];
        const float pz = xyz[3 * t + 2];
        const float s  = px * px + py * py + pz * pz;   // matches ref s = sum(xyz*xyz)
        pts[t] = make_float4(px, py, pz, s);
    }
}

// KNN, 4 queries per wave. lane = g*16+s: group g (query), slot s. The top-16
// list of each query lives across its group's 16 lanes (lane s = s-th
// smallest). Per chunk: 64 lanes evaluate 16 candidates x 4 queries (same
// candidate set, L1 broadcast). Survivors (d2 < tau_g, strict) are retired
// up to 4 per while-iteration (one per group, exec-masked lockstep) via a
// width-16 shuffle-shift insert. ctz-ascending within chunk + ascending
// chunks => ascending-j stream; strict < preserves reference lowest-index
// tie-break; stale-tau survivors self-reject.
__global__ __launch_bounds__(256) void knn_kernel(
    const float4* __restrict__ pts, unsigned short* __restrict__ knn)
{
    const int lane = threadIdx.x & 63;
    const int wid  = threadIdx.x >> 6;
    const int g    = lane >> 4;                 // group (query) 0..3
    const int s    = lane & 15;                 // slot within group
    const int wq   = blockIdx.x * 16 + wid * 4; // first query of this wave
    const int b    = wq >> 12;                  // 4 queries never cross a batch
    const int i    = (wq & 4095) + g;           // this lane's query
    const float4* pb = pts + (b << 12);

    const float4 q = pb[i];                     // group-uniform

    float bd = 3.4e38f;                         // slot s: s-th smallest
    int   bj = 0;
    float tau = 3.4e38f;                        // group-uniform (lane copy)
    const bool sgt0 = (s > 0);

    float4 p = pb[s];                           // chunk 0 candidates
    for (int ch = 0; ch < 256; ++ch) {
        const int nxt = (ch + 1 < 256) ? ((ch + 1) << 4) + s : s;
        const float4 pn = pb[nxt];              // prefetch next chunk
        float d2;
        {
            #pragma clang fp contract(off)
            const float cs  = p.w;
            const float dot = q.x * p.x + q.y * p.y + q.z * p.z;
            d2 = (q.w + cs) - 2.0f * dot;       // s_i + s_j - 2*dot, as ref
        }
        const unsigned long long mask = __ballot(d2 < tau);
        unsigned sub = (unsigned)((mask >> (g << 4)) & 0xFFFFull);
        while (__any(sub != 0)) {
            const bool has = (sub != 0);
            const int  l   = has ? (__ffs(sub) - 1) : 0;
            const float dv_raw = __shfl(d2, l, 16);      // group-local fetch
            const float dv = has ? dv_raw : 3.4e38f;
            const int   jv = (ch << 4) + l;
            sub = has ? (sub & (sub - 1)) : 0u;
            // sorted insert across the group's 16 lanes (ascending)
            const float pd = __shfl_up(bd, 1, 16);
            const int   pj = __shfl_up(bj, 1, 16);
            const bool lt  = dv < bd;
            const bool ltp = sgt0 && (dv < pd);
            bd = lt ? (ltp ? pd : dv) : bd;
            bj = lt ? (ltp ? pj : jv) : bj;
            tau = __shfl(bd, 15, 16);
        }
        p = pn;
    }

    unsigned short* o = knn + ((((size_t)b << 12) + i) << 4);
    o[s] = (unsigned short)bj;                  // 4 queries x 16 slots, contiguous
}

// Fused gather + GEMM(bf16 MFMA) + BN + ReLU + max-over-K.
// W staged in LDS (pitch 136 shorts: 272B row period -> 2-way-max bank alias).
__global__ __launch_bounds__(256) void gemm_kernel(
    const short* __restrict__ xTb, const short* __restrict__ Wb,
    const unsigned short* __restrict__ knn,
    const float* __restrict__ scale, const float* __restrict__ bias,
    float* __restrict__ out)
{
    __shared__ short sW[CCH * 136];
    const int lane = threadIdx.x & 63;
    const int wid  = threadIdx.x >> 6;
    const int b    = blockIdx.x >> 9;            // N/8 = 512 groups per batch
    const int ng   = blockIdx.x & 511;
    const int n0   = ng * 8 + wid * 2;           // this wave's two points
    const int kl   = lane & 15;                  // A: m-index = neighbor k; B: n-index = out ch
    const int c0   = (lane >> 4) * 8;            // k-dim sub-offset within 32-chunk

    #pragma unroll
    for (int it = 0; it < 8; ++it) {             // stage W: 16384 elems, 16B chunks
        const int e = (it * 256 + threadIdx.x) * 8;
        const int r = e >> 7, c = e & 127;
        *(bf16x8*)(sW + r * 136 + c) = *(const bf16x8*)(Wb + e);
    }

    int rowoff[2];
    #pragma unroll
    for (int p = 0; p < 2; ++p) {
        const int n = n0 + p;
        const int r = (int)knn[(((size_t)b * NPTS + n) << 4) + kl];
        rowoff[p] = (b * NPTS + r) * CCH;        // element offset into xTb
    }
    __syncthreads();

    const f32x4 zero = {0.f, 0.f, 0.f, 0.f};
    f32x4 acc[2][8];
    #pragma unroll
    for (int p = 0; p < 2; ++p)
        #pragma unroll
        for (int t = 0; t < 8; ++t) acc[p][t] = zero;

    #pragma unroll
    for (int kk = 0; kk < 4; ++kk) {             // K = 128 channels, 32 per MFMA
        const int cb = kk * 32 + c0;
        bf16x8 a0 = *(const bf16x8*)(xTb + rowoff[0] + cb);
        bf16x8 a1 = *(const bf16x8*)(xTb + rowoff[1] + cb);
        #pragma unroll
        for (int t = 0; t < 8; ++t) {
            const bf16x8 bf = *(const bf16x8*)(sW + (t * 16 + kl) * 136 + cb);
            acc[0][t] = __builtin_amdgcn_mfma_f32_16x16x32_bf16(a0, bf, acc[0][t], 0, 0, 0);
            acc[1][t] = __builtin_amdgcn_mfma_f32_16x16x32_bf16(a1, bf, acc[1][t], 0, 0, 0);
        }
    }

    #pragma unroll
    for (int t = 0; t < 8; ++t) {
        const int o = t * 16 + kl;
        const float s  = scale[o];
        const float bb = bias[o];
        #pragma unroll
        for (int p = 0; p < 2; ++p) {
            const f32x4 v = acc[p][t];
            float mx = 0.f;                      // relu floor: max_k relu(y) = max(0, max_k y)
            #pragma unroll
            for (int r = 0; r < 4; ++r) mx = fmaxf(mx, v[r] * s + bb);
            mx = fmaxf(mx, __shfl_xor(mx, 16));
            mx = fmaxf(mx, __shfl_xor(mx, 32));
            if (lane < 16) out[(size_t)(b * CCH + o) * NPTS + (n0 + p)] = mx;
        }
    }
}

extern "C" void kernel_launch(void* const* d_in, const int* in_sizes, int n_in,
                              void* d_out, int out_size, void* d_ws, size_t ws_size,
                              hipStream_t stream)
{
    const float* xyz   = (const float*)d_in[0];
    const float* x     = (const float*)d_in[1];
    const float* W     = (const float*)d_in[2];
    const float* gamma = (const float*)d_in[3];
    const float* beta  = (const float*)d_in[4];
    const float* rmean = (const float*)d_in[5];
    const float* rvar  = (const float*)d_in[6];
    float* out = (float*)d_out;

    char* ws = (char*)d_ws;
    short*          xTb   = (short*)(ws);
    short*          Wb    = (short*)(ws + 8388608);
    float*          scale = (float*)(ws + 8421376);
    float*          bias  = (float*)(ws + 8421888);
    float4*         pts   = (float4*)(ws + 8422400);
    unsigned short* knn   = (unsigned short*)(ws + 8946688);

    transpose_kernel<<<BATCH * 64 * 2, 256, 0, stream>>>(x, xTb);
    small_prep_kernel<<<BATCH * NPTS / 256, 256, 0, stream>>>(
        xyz, W, gamma, beta, rmean, rvar, Wb, scale, bias, pts);
    knn_kernel<<<BATCH * NPTS / 16, 256, 0, stream>>>(pts, knn);
    gemm_kernel<<<BATCH * (NPTS / 8), 256, 0, stream>>>(xTb, Wb, knn, scale, bias, out);
}

// Round 9
// 212.603 us; speedup vs baseline: 16.9825x; 1.1174x over previous
//
#include <hip/hip_runtime.h>
#include <hip/hip_bf16.h>

// Problem constants (fixed by the reference)
#define BATCH 8
#define NPTS  4096      // N
#define CCH   128      // C
#define KNN_K 16       // K

typedef __attribute__((ext_vector_type(8))) short  bf16x8;  // 8 bf16 = 4 VGPRs
typedef __attribute__((ext_vector_type(4))) float  f32x4;   // MFMA acc

// ---------------------------------------------------------------------------
// ws layout (bytes):
//   [0)          xTb   : B*N*C bf16      = 8,388,608
//   [8388608)    Wb    : C*C  bf16       =    32,768
//   [8421376)    scale : C fp32          =       512
//   [8421888)    bias  : C fp32          =       512
//   [8422400)    pts   : B*N float4(x,y,z,s) = 524,288
//   [8946688)    knn   : B*N*K u16       = 1,048,576
//   [9995264)    Zb    : B*N*C bf16      = 8,388,608   (Z = W@x, [B,N,C])
// total 18,383,872
// ---------------------------------------------------------------------------

static __device__ __forceinline__ short f2bf(float v) {
    __hip_bfloat16 h = __float2bfloat16(v);   // RNE
    return __builtin_bit_cast(short, h);
}

// LDS-tiled transpose: x [B,C,N] fp32 -> xTb [B,N,C] bf16.
__global__ __launch_bounds__(256) void transpose_kernel(
    const float* __restrict__ x, short* __restrict__ xTb)
{
    __shared__ short tile[64 * 66];
    const int tid = threadIdx.x;
    const int b   = blockIdx.x >> 7;         // 8 batches
    const int rem = blockIdx.x & 127;
    const int nt  = rem >> 1;                // 64 n-tiles of 64
    const int ct  = rem & 1;                 // 2 c-tiles of 64

    #pragma unroll
    for (int it = 0; it < 16; ++it) {
        const int idx = it * 256 + tid;
        const int cc  = idx >> 6;
        const int nn  = idx & 63;
        const float v = x[(size_t)(b * CCH + ct * 64 + cc) * NPTS + nt * 64 + nn];
        tile[cc * 66 + nn] = f2bf(v);
    }
    __syncthreads();
    #pragma unroll
    for (int it = 0; it < 16; ++it) {
        const int idx = it * 256 + tid;
        const int nn  = idx >> 6;
        const int cc  = idx & 63;
        xTb[(size_t)(b * NPTS + nt * 64 + nn) * CCH + ct * 64 + cc] = tile[cc * 66 + nn];
    }
}

// Small prep: W -> bf16; fold BN affine; xyz -> SoA float4 with |p|^2
__global__ __launch_bounds__(256) void small_prep_kernel(
    const float* __restrict__ xyz, const float* __restrict__ W,
    const float* __restrict__ gamma, const float* __restrict__ beta,
    const float* __restrict__ rmean, const float* __restrict__ rvar,
    short* __restrict__ Wb, float* __restrict__ scale, float* __restrict__ bias,
    float4* __restrict__ pts)
{
    const int t = blockIdx.x * 256 + threadIdx.x;   // grid covers B*N = 32768
    if (t < CCH * CCH) Wb[t] = f2bf(W[t]);
    if (t < CCH) {
        const float s = gamma[t] / sqrtf(rvar[t] + 1e-5f);
        scale[t] = s;
        bias[t]  = beta[t] - rmean[t] * s;
    }
    {
        #pragma clang fp contract(off)
        const float px = xyz[3 * t + 0];
        const float py = xyz[3 * t + 1];
        const float pz = xyz[3 * t + 2];
        const float s  = px * px + py * py + pz * pz;   // matches ref s = sum(xyz*xyz)
        pts[t] = make_float4(px, py, pz, s);
    }
}

// KNN, 4 queries per wave. lane = g*16+s. Top-16 list of each query lives
// across its group's 16 lanes (lane s = s-th smallest). Survivors retired up
// to 4 per while-iteration via width-16 shuffle-shift insert. tau broadcast
// hoisted out of the insert loop (dead within a chunk: the ballot is already
// taken; stale-tau survivors self-reject in the insert). ctz-ascending +
// ascending chunks => ascending-j; strict < preserves reference tie-break.
__global__ __launch_bounds__(256) void knn_kernel(
    const float4* __restrict__ pts, unsigned short* __restrict__ knn)
{
    const int lane = threadIdx.x & 63;
    const int wid  = threadIdx.x >> 6;
    const int g    = lane >> 4;                 // group (query) 0..3
    const int s    = lane & 15;                 // slot within group
    const int wq   = blockIdx.x * 16 + wid * 4; // first query of this wave
    const int b    = wq >> 12;                  // 4 queries never cross a batch
    const int i    = (wq & 4095) + g;           // this lane's query
    const float4* pb = pts + (b << 12);

    const float4 q = pb[i];                     // group-uniform

    float bd = 3.4e38f;                         // slot s: s-th smallest
    int   bj = 0;
    float tau = 3.4e38f;                        // group-uniform (lane copy)
    const bool sgt0 = (s > 0);

    float4 p = pb[s];                           // chunk 0 candidates
    for (int ch = 0; ch < 256; ++ch) {
        const int nxt = (ch + 1 < 256) ? ((ch + 1) << 4) + s : s;
        const float4 pn = pb[nxt];              // prefetch next chunk
        float d2;
        {
            #pragma clang fp contract(off)
            const float cs  = p.w;
            const float dot = q.x * p.x + q.y * p.y + q.z * p.z;
            d2 = (q.w + cs) - 2.0f * dot;       // s_i + s_j - 2*dot, as ref
        }
        const unsigned long long mask = __ballot(d2 < tau);
        unsigned sub = (unsigned)((mask >> (g << 4)) & 0xFFFFull);
        while (__any(sub != 0)) {
            const bool has = (sub != 0);
            const int  l   = has ? (__ffs(sub) - 1) : 0;
            const float dv_raw = __shfl(d2, l, 16);      // group-local fetch
            const float dv = has ? dv_raw : 3.4e38f;
            const int   jv = (ch << 4) + l;
            sub = has ? (sub & (sub - 1)) : 0u;
            // sorted insert across the group's 16 lanes (ascending)
            const float pd = __shfl_up(bd, 1, 16);
            const int   pj = __shfl_up(bj, 1, 16);
            const bool lt  = dv < bd;
            const bool ltp = sgt0 && (dv < pd);
            bd = lt ? (ltp ? pd : dv) : bd;
            bj = lt ? (ltp ? pj : jv) : bj;
        }
        tau = __shfl(bd, 15, 16);               // once per chunk (see note)
        p = pn;
    }

    unsigned short* o = knn + ((((size_t)b << 12) + i) << 4);
    o[s] = (unsigned short)bj;                  // 4 queries x 16 slots
}

// Dense GEMM: Z[g, c] = sum_k xTb[g, k] * W[c, k], Z bf16 [B*N, C].
// Wave = 16 rows x 128 cols; verified fragment mappings (A: m=lane&15,
// k=(lane>>4)*8+j; B: n=lane&15, same k-slice; C/D: col=lane&15,
// row=(lane>>4)*4+reg). W staged in LDS, pitch 136.
__global__ __launch_bounds__(256) void zgemm_kernel(
    const short* __restrict__ xTb, const short* __restrict__ Wb,
    short* __restrict__ Zb)
{
    __shared__ short sW[CCH * 136];
    const int lane = threadIdx.x & 63;
    const int wid  = threadIdx.x >> 6;
    const int kl   = lane & 15;
    const int q8   = (lane >> 4) * 8;

    #pragma unroll
    for (int it = 0; it < 8; ++it) {             // stage W: 16384 elems
        const int e = (it * 256 + threadIdx.x) * 8;
        const int r = e >> 7, c = e & 127;
        *(bf16x8*)(sW + r * 136 + c) = *(const bf16x8*)(Wb + e);
    }

    const int    G    = blockIdx.x * 64 + wid * 16 + kl;   // A-row (flat B*N)
    const size_t arow = (size_t)G * CCH;
    __syncthreads();

    const f32x4 zero = {0.f, 0.f, 0.f, 0.f};
    f32x4 acc[8];
    #pragma unroll
    for (int t = 0; t < 8; ++t) acc[t] = zero;

    #pragma unroll
    for (int kk = 0; kk < 4; ++kk) {
        const bf16x8 a = *(const bf16x8*)(xTb + arow + kk * 32 + q8);
        #pragma unroll
        for (int t = 0; t < 8; ++t) {
            const bf16x8 bf = *(const bf16x8*)(sW + (t * 16 + kl) * 136 + kk * 32 + q8);
            acc[t] = __builtin_amdgcn_mfma_f32_16x16x32_bf16(a, bf, acc[t], 0, 0, 0);
        }
    }

    const int rbase = blockIdx.x * 64 + wid * 16 + (lane >> 4) * 4;
    #pragma unroll
    for (int t = 0; t < 8; ++t)
        #pragma unroll
        for (int r = 0; r < 4; ++r)
            Zb[(size_t)(rbase + r) * CCH + t * 16 + kl] = f2bf(acc[t][r]);
}

// Gather + BN + ReLU + max-over-16, then coalesced store via LDS transpose.
// Block = 16 points; wave w handles 4 points serially; lane l covers channels
// 2l, 2l+1 (one dword per Z-row read; full 256B row per wave, coalesced).
__global__ __launch_bounds__(256) void gmax_kernel(
    const short* __restrict__ Zb, const unsigned short* __restrict__ knn,
    const float* __restrict__ scale, const float* __restrict__ bias,
    float* __restrict__ out)
{
    __shared__ float sm[16][132];
    const int lane = threadIdx.x & 63;
    const int wid  = threadIdx.x >> 6;
    const int n0   = blockIdx.x * 16;           // flat point base (B*N)
    const int b    = blockIdx.x >> 8;           // 256 blocks per batch
    const float s0 = scale[2 * lane],   s1 = scale[2 * lane + 1];
    const float t0 = bias[2 * lane],    t1 = bias[2 * lane + 1];

    for (int p = 0; p < 4; ++p) {
        const int n = n0 + wid * 4 + p;         // flat
        const unsigned short* kr = knn + (size_t)n * 16;
        float m0 = 0.f, m1 = 0.f;               // relu floor
        #pragma unroll
        for (int k = 0; k < 16; ++k) {
            const int r = (int)kr[k];           // within-batch row
            const unsigned v = *(const unsigned*)(Zb + ((size_t)(b * NPTS + r)) * CCH + 2 * lane);
            const float z0 = __uint_as_float(v << 16);
            const float z1 = __uint_as_float(v & 0xFFFF0000u);
            m0 = fmaxf(m0, s0 * z0 + t0);
            m1 = fmaxf(m1, s1 * z1 + t1);
        }
        sm[wid * 4 + p][2 * lane]     = m0;
        sm[wid * 4 + p][2 * lane + 1] = m1;
    }
    __syncthreads();

    const int c    = threadIdx.x & 127;
    const int half = threadIdx.x >> 7;
    float v[8];
    #pragma unroll
    for (int i = 0; i < 8; ++i) v[i] = sm[half * 8 + i][c];
    float4 f0 = {v[0], v[1], v[2], v[3]};
    float4 f1 = {v[4], v[5], v[6], v[7]};
    float* op = out + ((size_t)(b * CCH + c)) * NPTS + (n0 & 4095) + half * 8;
    *(float4*)op       = f0;
    *(float4*)(op + 4) = f1;
}

extern "C" void kernel_launch(void* const* d_in, const int* in_sizes, int n_in,
                              void* d_out, int out_size, void* d_ws, size_t ws_size,
                              hipStream_t stream)
{
    const float* xyz   = (const float*)d_in[0];
    const float* x     = (const float*)d_in[1];
    const float* W     = (const float*)d_in[2];
    const float* gamma = (const float*)d_in[3];
    const float* beta  = (const float*)d_in[4];
    const float* rmean = (const float*)d_in[5];
    const float* rvar  = (const float*)d_in[6];
    float* out = (float*)d_out;

    char* ws = (char*)d_ws;
    short*          xTb   = (short*)(ws);
    short*          Wb    = (short*)(ws + 8388608);
    float*          scale = (float*)(ws + 8421376);
    float*          bias  = (float*)(ws + 8421888);
    float4*         pts   = (float4*)(ws + 8422400);
    unsigned short* knn   = (unsigned short*)(ws + 8946688);
    short*          Zb    = (short*)(ws + 9995264);

    transpose_kernel<<<BATCH * 64 * 2, 256, 0, stream>>>(x, xTb);
    small_prep_kernel<<<BATCH * NPTS / 256, 256, 0, stream>>>(
        xyz, W, gamma, beta, rmean, rvar, Wb, scale, bias, pts);
    knn_kernel<<<BATCH * NPTS / 16, 256, 0, stream>>>(pts, knn);
    zgemm_kernel<<<BATCH * NPTS / 64, 256, 0, stream>>>(xTb, Wb, Zb);
    gmax_kernel<<<BATCH * NPTS / 16, 256, 0, stream>>>(Zb, knn, scale, bias, out);
}